// Round 9
// baseline (48.167 us; speedup 1.0000x reference)
//
#include <hip/hip_runtime.h>
#include <hip/hip_bf16.h>

#define CIN 65
#define LIN 577
#define NT  9        // K-tiles of 64 = taps m (576 = 9*64); t_resc = rank-1 epilogue
#define M_  16384

typedef __bf16 bf16x8 __attribute__((ext_vector_type(8)));
typedef float  f32x4  __attribute__((ext_vector_type(4)));
typedef unsigned short u16x8 __attribute__((ext_vector_type(8)));

// SIG[r] = flatten(rot90(arange(9).reshape(3,3), r)); SIG[(4-g)&3] = sigma_g^{-1}
__constant__ int SIG[4][9] = {
  {0,1,2,3,4,5,6,7,8},
  {2,5,8,1,4,7,0,3,6},
  {8,7,6,5,4,3,2,1,0},
  {6,3,0,7,4,1,8,5,2}};

// ---- kernel 1 (fused): blocks [0,256): im2col -> A[q=m*8+cb][row 16384][8] + T
//                        blocks [256,400): W -> Wg[g*9+m][col 256][64] bf16
__global__ __launch_bounds__(512) void prep_k(const float* __restrict__ x,
                                              const float* __restrict__ W,
                                              __hip_bfloat16* __restrict__ A,
                                              __hip_bfloat16* __restrict__ Wg,
                                              float* __restrict__ T) {
  __shared__ float lds[CIN * 3 * 72];   // [c][dy][slot 4+u], u = x-pos in [-1,64]
  const int tid = threadIdx.x;
  if (blockIdx.x >= 256) {              // ---- weight prep branch ----
    int pidx = (blockIdx.x - 256) * 512 + tid;   // 0..73727
    int jc  = pidx & 7;
    int col = (pidx >> 3) & 255;
    int t   = pidx >> 11;               // g*9 + m
    int m   = t % NT, g = t / NT;
    int k   = SIG[(4 - g) & 3][m];
    const float* src = W + col * LIN + 1 + k * 64 + jc * 8;
    u16x8 pk;
#pragma unroll
    for (int e = 0; e < 8; ++e) {
      union { __hip_bfloat16 h; unsigned short u; } cv;
      cv.h = __float2bfloat16(src[e]);
      pk[e] = cv.u;
    }
    *(u16x8*)(Wg + (size_t)pidx * 8) = pk;
    return;
  }
  // ---- im2col branch ----
  const int b = blockIdx.x >> 6, py = blockIdx.x & 63;
  const float* xb = x + (size_t)b * (CIN * 4096);
  for (int i = tid; i < CIN * 3 * 18; i += 512)
    *(f32x4*)&lds[i * 4] = (f32x4){0.f, 0.f, 0.f, 0.f};
  __syncthreads();
  for (int i = tid; i < CIN * 3 * 16; i += 512) {
    int pr = i >> 4, j = i & 15;
    int c = pr / 3, dy = pr - c * 3;
    int hy = py + dy - 1;
    if (hy >= 0 && hy < 64)
      *(f32x4*)&lds[c * 216 + dy * 72 + 4 + j * 4] =
          *(const f32x4*)(xb + c * 4096 + hy * 64 + j * 4);
  }
  __syncthreads();

  const int wave = tid >> 6, px = tid & 63;
  const int rowid = (blockIdx.x << 6) | px;
#pragma unroll
  for (int qi = 0; qi < 9; ++qi) {
    int q = wave * 9 + qi;               // q = m*8 + cb8 (chunk of 8 channels)
    int m = q >> 3, cb8 = q & 7;
    int dy = m / 3, dx = m - dy * 3;
    const float* src = &lds[(1 + cb8 * 8) * 216 + dy * 72 + 3 + dx + px];
    u16x8 pk;
#pragma unroll
    for (int e = 0; e < 8; ++e) {
      union { __hip_bfloat16 h; unsigned short u; } cv;
      cv.h = __float2bfloat16(src[e * 216]);
      pk[e] = cv.u;
    }
    *(u16x8*)(A + ((size_t)q * M_ + rowid) * 8) = pk;   // dense 16B/lane
  }
  if (wave == 0) {   // t_resc (rotation-invariant)
    float s = 0.f;
#pragma unroll
    for (int m = 0; m < 9; ++m) {
      float t = fmaxf(lds[(m / 3) * 72 + 3 + (m % 3) + px], 1.f);
      s += t * t;
    }
    T[rowid] = sqrtf(s - 8.f);
  }
}

// ---- kernel 2: 8-phase GEMM (m201-style). BM=256 BN=256 BK=64, 1 block/CU -
__device__ __forceinline__ void async_cp16(const void* g, void* ldsbase) {
  __builtin_amdgcn_global_load_lds(
      (const __attribute__((address_space(1))) void*)g,
      (__attribute__((address_space(3))) void*)ldsbase, 16, 0, 0);
}

__global__ __launch_bounds__(512, 2) void gemm_k(const __hip_bfloat16* __restrict__ A,
                                                 const __hip_bfloat16* __restrict__ Wg,
                                                 const float* __restrict__ W,
                                                 const float* __restrict__ bias,
                                                 const float* __restrict__ T,
                                                 float* __restrict__ out) {
  // A slots @0/32K (each [256 r][64 k] bf16), B slots @64K/96K (each [256 c][64 k])
  __shared__ __align__(16) char smem[131072];
  const int fid = blockIdx.x;
  const int lid = ((fid & 7) << 5) | (fid >> 3);   // g-siblings co-XCD, bijective
  const int g = lid & 3, rb = lid >> 2;
  const int brow = rb << 8;
  const int tid = threadIdx.x, wave = tid >> 6, lane = tid & 63;
  const int fr = lane & 15, fq = lane >> 4;
  const int wr = (wave >> 2) * 128, wcb = (wave & 3) * 64;
  const __hip_bfloat16* Wgb = Wg + ((size_t)(g * NT) << 14);
  f32x4 acc[8][4] = {};

  // staging: LDS linear [r][8 phys chunks of 16B]; source supplies logical
  // chunk lc = pc ^ (r&7)  (rule #21: inverse-swizzled source, swizzled read)
  auto STAGE_A = [&](char* slot, int kt, int l0) {
#pragma unroll
    for (int l = l0; l < l0 + 2; ++l) {
      int u = l * 512 + tid, r = u >> 3, lc = (u & 7) ^ (r & 7);
      async_cp16(A + (((size_t)(kt * 8 + lc) * M_ + brow + r) << 3),
                 slot + (l * 512 + wave * 64) * 16);
    }
  };
  auto STAGE_B = [&](char* slot, int kt, int l0) {
#pragma unroll
    for (int l = l0; l < l0 + 2; ++l) {
      int u = l * 512 + tid, c = u >> 3, lc = (u & 7) ^ (c & 7);
      async_cp16(Wgb + ((size_t)kt << 14) + c * 64 + lc * 8,
                 slot + (l * 512 + wave * 64) * 16);
    }
  };
  auto LDA = [&](const char* As, bf16x8* af, int kk, int ih) {
#pragma unroll
    for (int i = 0; i < 4; ++i) {
      int r = wr + ih * 64 + i * 16 + fr;
      af[i] = *(const bf16x8*)(As + r * 128 + (((kk * 4 + fq) ^ (r & 7)) << 4));
    }
  };
  auto LDB = [&](const char* Bs, bf16x8* bf, int kk) {
#pragma unroll
    for (int j = 0; j < 4; ++j) {
      int c = wcb + j * 16 + fr;
      bf[j] = *(const bf16x8*)(Bs + c * 128 + (((kk * 4 + fq) ^ (c & 7)) << 4));
    }
  };
  auto MM = [&](const bf16x8* af, const bf16x8* bf, int ih) {
    __builtin_amdgcn_s_setprio(1);
#pragma unroll
    for (int i = 0; i < 4; ++i)
#pragma unroll
      for (int j = 0; j < 4; ++j)
        acc[ih * 4 + i][j] =
            __builtin_amdgcn_mfma_f32_16x16x32_bf16(af[i], bf[j], acc[ih * 4 + i][j], 0, 0, 0);
    __builtin_amdgcn_s_setprio(0);
  };

  STAGE_A(smem, 0, 0); STAGE_A(smem, 0, 2);
  STAGE_B(smem + 65536, 0, 0); STAGE_B(smem + 65536, 0, 2);
  asm volatile("s_waitcnt vmcnt(0)" ::: "memory");
  __builtin_amdgcn_s_barrier();
  __builtin_amdgcn_sched_barrier(0);

  for (int kt = 0; kt < NT; ++kt) {
    const int cb = (kt & 1) * 32768, nb = 32768 - cb;
    const char* As = smem + cb;
    const char* Bs = smem + 65536 + cb;
    char* An = smem + nb;
    char* Bn = smem + 65536 + nb;
    const bool pf = (kt + 1 < NT);
    bf16x8 af[4], bf[4];
    // P0: af(ih0,kk0)+bf(kk0) | stage A(t+1) half0 | MFMA quad (ih0,kk0)
    LDA(As, af, 0, 0); LDB(Bs, bf, 0);
    if (pf) STAGE_A(An, kt + 1, 0);
    __builtin_amdgcn_s_barrier();
    asm volatile("s_waitcnt lgkmcnt(0)" ::: "memory");
    __builtin_amdgcn_sched_barrier(0);
    MM(af, bf, 0);
    __builtin_amdgcn_s_barrier();
    __builtin_amdgcn_sched_barrier(0);
    // P1: af(ih1,kk0) | stage A(t+1) half1 | MFMA (ih1,kk0)
    LDA(As, af, 0, 1);
    if (pf) STAGE_A(An, kt + 1, 2);
    __builtin_amdgcn_s_barrier();
    asm volatile("s_waitcnt lgkmcnt(0)" ::: "memory");
    __builtin_amdgcn_sched_barrier(0);
    MM(af, bf, 1);
    __builtin_amdgcn_s_barrier();
    __builtin_amdgcn_sched_barrier(0);
    // P2: af(ih0,kk1)+bf(kk1) | stage B(t+1) half0 | MFMA (ih0,kk1)
    LDA(As, af, 1, 0); LDB(Bs, bf, 1);
    if (pf) STAGE_B(Bn, kt + 1, 0);
    __builtin_amdgcn_s_barrier();
    asm volatile("s_waitcnt lgkmcnt(0)" ::: "memory");
    __builtin_amdgcn_sched_barrier(0);
    MM(af, bf, 0);
    __builtin_amdgcn_s_barrier();
    __builtin_amdgcn_sched_barrier(0);
    // P3: af(ih1,kk1) | stage B(t+1) half1 | MFMA (ih1,kk1) | tile-end drain
    LDA(As, af, 1, 1);
    if (pf) STAGE_B(Bn, kt + 1, 2);
    __builtin_amdgcn_s_barrier();
    asm volatile("s_waitcnt lgkmcnt(0)" ::: "memory");
    __builtin_amdgcn_sched_barrier(0);
    MM(af, bf, 1);
    asm volatile("s_waitcnt vmcnt(0)" ::: "memory");  // once per K-tile; loads had ~4 phases
    __builtin_amdgcn_s_barrier();
    __builtin_amdgcn_sched_barrier(0);
  }

  // epilogue: y = acc + bias + t*W[:,0]; store y (o!=0); fused Lorentz norm
  float* Ps = (float*)smem;   // [256][4], safe: all LDS reads done before last barrier
  float bo[4], w0v[4]; int oc[4];
#pragma unroll
  for (int j = 0; j < 4; ++j) {
    oc[j]  = wcb + j * 16 + fr;
    bo[j]  = bias[oc[j]];
    w0v[j] = W[oc[j] * LIN];
  }
#pragma unroll
  for (int i = 0; i < 8; ++i) {
#pragma unroll
    for (int rr = 0; rr < 4; ++rr) {
      int rl = wr + i * 16 + fq * 4 + rr;
      int row = brow + rl;
      size_t obase = ((size_t)(((row >> 12) * 4 + g) * 4096 + (row & 4095)) << 8);
      float tval = T[row];
      float s = 0.f;
#pragma unroll
      for (int j = 0; j < 4; ++j) {
        float y = acc[i][j][rr] + bo[j] + tval * w0v[j];
        if (oc[j] != 0) { s += y * y; out[obase + oc[j]] = y; }
      }
      s += __shfl_xor(s, 1); s += __shfl_xor(s, 2);
      s += __shfl_xor(s, 4); s += __shfl_xor(s, 8);
      if (fr == 0) Ps[rl * 4 + (wave & 3)] = s;
    }
  }
  __syncthreads();
  if (tid < 256) {
    int row = brow + tid;
    float s = Ps[tid * 4] + Ps[tid * 4 + 1] + Ps[tid * 4 + 2] + Ps[tid * 4 + 3] + 1.0f;
    out[(size_t)(((row >> 12) * 4 + g) * 4096 + (row & 4095)) << 8] = sqrtf(s);
  }
}

extern "C" void kernel_launch(void* const* d_in, const int* in_sizes, int n_in,
                              void* d_out, int out_size, void* d_ws, size_t ws_size,
                              hipStream_t stream) {
  const float* x    = (const float*)d_in[0];
  const float* W    = (const float*)d_in[1];
  const float* bias = (const float*)d_in[2];
  float* out = (float*)d_out;

  char* ws = (char*)d_ws;
  __hip_bfloat16* Wg = (__hip_bfloat16*)ws;                 // 36*256*64*2 = 1179648 B
  float*          T  = (float*)(ws + 1179648);              // 65536 B
  __hip_bfloat16* A  = (__hip_bfloat16*)(ws + 1245184);     // 72*16384*8*2 = 18874368 B

  prep_k<<<400, 512, 0, stream>>>(x, W, A, Wg, T);
  gemm_k<<<256, 512, 0, stream>>>(A, Wg, W, bias, T, out);
}

// Round 10
// 46.330 us; speedup vs baseline: 1.0396x; 1.0396x over previous
//
#include <hip/hip_runtime.h>
#include <hip/hip_bf16.h>

#define CIN 65
#define LIN 577
#define NSTEP 18      // K = 576 = 18 steps of 32; t_resc is a rank-1 epilogue
#define M_  16384

typedef __bf16 bf16x8 __attribute__((ext_vector_type(8)));
typedef float  f32x4  __attribute__((ext_vector_type(4)));
typedef unsigned short u16x8 __attribute__((ext_vector_type(8)));

// SIG[r] = flatten(rot90(arange(9).reshape(3,3), r)); SIG[(4-g)&3] = sigma_g^{-1}
__constant__ int SIG[4][9] = {
  {0,1,2,3,4,5,6,7,8},
  {2,5,8,1,4,7,0,3,6},
  {8,7,6,5,4,3,2,1,0},
  {6,3,0,7,4,1,8,5,2}};

// XOR mask for the 4 16B-chunks of a 64B LDS row (2-way max bank aliasing = free)
__device__ __forceinline__ int swzm(int r) { return (r ^ (r >> 2)) & 3; }

// ---- kernel 1 (fused): blocks [0,256): im2col -> A[q 72][row 16384][8] + T
//                        blocks [256,400): W -> Wg[g*18+ks][col 256][32] bf16
__global__ __launch_bounds__(512) void prep_k(const float* __restrict__ x,
                                              const float* __restrict__ W,
                                              __hip_bfloat16* __restrict__ A,
                                              __hip_bfloat16* __restrict__ Wg,
                                              float* __restrict__ T) {
  __shared__ float lds[CIN * 3 * 72];   // [c][dy][slot 4+u], u = x-pos in [-1,64]
  const int tid = threadIdx.x;
  if (blockIdx.x >= 256) {              // ---- weight prep branch ----
    int pidx = (blockIdx.x - 256) * 512 + tid;   // 0..73727
    int jc  = pidx & 3;
    int col = (pidx >> 2) & 255;
    int t   = pidx >> 10;               // g*18 + ks
    int ks  = t % NSTEP, g = t / NSTEP;
    int k   = SIG[(4 - g) & 3][ks >> 1];
    const float* src = W + col * LIN + 1 + k * 64 + (ks & 1) * 32 + jc * 8;
    u16x8 pk;
#pragma unroll
    for (int e = 0; e < 8; ++e) {
      union { __hip_bfloat16 h; unsigned short u; } cv;
      cv.h = __float2bfloat16(src[e]);
      pk[e] = cv.u;
    }
    *(u16x8*)(Wg + (size_t)pidx * 8) = pk;
    return;
  }
  // ---- im2col branch ----
  const int b = blockIdx.x >> 6, py = blockIdx.x & 63;
  const float* xb = x + (size_t)b * (CIN * 4096);
  for (int i = tid; i < CIN * 3 * 18; i += 512)
    *(f32x4*)&lds[i * 4] = (f32x4){0.f, 0.f, 0.f, 0.f};
  __syncthreads();
  for (int i = tid; i < CIN * 3 * 16; i += 512) {
    int pr = i >> 4, j = i & 15;
    int c = pr / 3, dy = pr - c * 3;
    int hy = py + dy - 1;
    if (hy >= 0 && hy < 64)
      *(f32x4*)&lds[c * 216 + dy * 72 + 4 + j * 4] =
          *(const f32x4*)(xb + c * 4096 + hy * 64 + j * 4);
  }
  __syncthreads();

  const int wave = tid >> 6, px = tid & 63;
  const int rowid = (blockIdx.x << 6) | px;
#pragma unroll
  for (int qi = 0; qi < 9; ++qi) {
    int q = wave * 9 + qi;               // q = m*8 + cb8 (chunk of 8 channels)
    int m = q >> 3, cb8 = q & 7;
    int dy = m / 3, dx = m - dy * 3;
    const float* src = &lds[(1 + cb8 * 8) * 216 + dy * 72 + 3 + dx + px];
    u16x8 pk;
#pragma unroll
    for (int e = 0; e < 8; ++e) {
      union { __hip_bfloat16 h; unsigned short u; } cv;
      cv.h = __float2bfloat16(src[e * 216]);
      pk[e] = cv.u;
    }
    *(u16x8*)(A + ((size_t)q * M_ + rowid) * 8) = pk;   // dense 16B/lane
  }
  if (wave == 0) {   // t_resc (rotation-invariant)
    float s = 0.f;
#pragma unroll
    for (int m = 0; m < 9; ++m) {
      float t = fmaxf(lds[(m / 3) * 72 + 3 + (m % 3) + px], 1.f);
      s += t * t;
    }
    T[rowid] = sqrtf(s - 8.f);
  }
}

// ---- kernel 2: GEMM BM=64 BN=256 BK=32, 256 thr, 4 blocks/CU (TLP) --------
// A fragments global->reg; B double-buffered in LDS via global_load_lds.
__device__ __forceinline__ void async_cp16(const void* g, void* ldsbase) {
  __builtin_amdgcn_global_load_lds(
      (const __attribute__((address_space(1))) void*)g,
      (__attribute__((address_space(3))) void*)ldsbase, 16, 0, 0);
}

__global__ __launch_bounds__(256, 4) void gemm_k(const __hip_bfloat16* __restrict__ A,
                                                 const __hip_bfloat16* __restrict__ Wg,
                                                 const float* __restrict__ W,
                                                 const float* __restrict__ bias,
                                                 const float* __restrict__ T,
                                                 float* __restrict__ out) {
  __shared__ __align__(16) char smem[32768];   // B0 16K | B1 16K; Ps aliases B0
  const int g = blockIdx.x >> 8, rb = blockIdx.x & 255;   // fid%8 = rb%8 -> g-siblings co-XCD
  const int brow = rb << 6;
  const int tid = threadIdx.x, wave = tid >> 6, lane = tid & 63;
  const int fr = lane & 15, fq = lane >> 4;
  const int wcb = wave * 64;

  // B staging: LDS dest linear, global source chunk-permuted (rule #21)
  const int bc  = tid >> 2;            // col handled by this thread (per l-round: +64)
  const __hip_bfloat16* Wgg = Wg + ((size_t)(g * NSTEP) << 13);
  auto STAGE_B = [&](char* pb, int ks) {
    const __hip_bfloat16* bs = Wgg + ((size_t)ks << 13);
#pragma unroll
    for (int l = 0; l < 4; ++l) {
      int c = l * 64 + bc;
      int lc = (tid & 3) ^ swzm(c);
      async_cp16(bs + c * 32 + lc * 8, pb + (l * 256 + wave * 64) * 16);
    }
  };
  // A fragments: chunk q = 4*ks + fq, row = brow + i*16 + fr
  const __hip_bfloat16* Alane = A + (((size_t)fq * M_ + brow + fr) << 3);
  bf16x8 af[4];
  auto LOAD_A = [&](int ks) {
#pragma unroll
    for (int i = 0; i < 4; ++i)
      af[i] = *(const bf16x8*)(Alane + (size_t)ks * (M_ * 32) + i * 128);
  };

  f32x4 acc[4][4] = {};
  auto COMPUTE = [&](const char* Bb) {
    bf16x8 bf[4];
#pragma unroll
    for (int j = 0; j < 4; ++j) {
      int c = wcb + j * 16 + fr;
      bf[j] = *(const bf16x8*)(Bb + c * 64 + ((fq ^ swzm(c)) << 4));
    }
    __builtin_amdgcn_s_setprio(1);
#pragma unroll
    for (int i = 0; i < 4; ++i)
#pragma unroll
      for (int j = 0; j < 4; ++j)
        acc[i][j] = __builtin_amdgcn_mfma_f32_16x16x32_bf16(af[i], bf[j], acc[i][j], 0, 0, 0);
    __builtin_amdgcn_s_setprio(0);
  };

  STAGE_B(smem, 0);
  for (int ks = 0; ks < NSTEP; ++ks) {
    LOAD_A(ks);                                        // 4 globals, newest
    asm volatile("s_waitcnt vmcnt(4)" ::: "memory");   // B(ks) drained; af in flight
    __builtin_amdgcn_s_barrier();                      // all waves' B(ks) resident
    if (ks + 1 < NSTEP) STAGE_B(smem + ((ks + 1) & 1) * 16384, ks + 1);
    COMPUTE(smem + (ks & 1) * 16384);                  // compiler waits af regs
  }
  __syncthreads();   // mainloop done; B0 region reusable as Ps

  // epilogue: y = acc + bias + t*W[:,0]; store y (o!=0); fused Lorentz norm
  float* Ps = (float*)smem;   // [64][4]
  float bo[4], w0v[4]; int oc[4];
#pragma unroll
  for (int j = 0; j < 4; ++j) {
    oc[j]  = wcb + j * 16 + fr;
    bo[j]  = bias[oc[j]];
    w0v[j] = W[oc[j] * LIN];
  }
#pragma unroll
  for (int i = 0; i < 4; ++i) {
#pragma unroll
    for (int rr = 0; rr < 4; ++rr) {
      int rl = i * 16 + fq * 4 + rr;
      int row = brow + rl;
      size_t obase = ((size_t)(((row >> 12) * 4 + g) * 4096 + (row & 4095)) << 8);
      float tval = T[row];
      float s = 0.f;
#pragma unroll
      for (int j = 0; j < 4; ++j) {
        float y = acc[i][j][rr] + bo[j] + tval * w0v[j];
        if (oc[j] != 0) { s += y * y; out[obase + oc[j]] = y; }
      }
      s += __shfl_xor(s, 1); s += __shfl_xor(s, 2);
      s += __shfl_xor(s, 4); s += __shfl_xor(s, 8);
      if (fr == 0) Ps[rl * 4 + wave] = s;
    }
  }
  __syncthreads();
  if (tid < 64) {
    int row = brow + tid;
    float s = Ps[tid * 4] + Ps[tid * 4 + 1] + Ps[tid * 4 + 2] + Ps[tid * 4 + 3] + 1.0f;
    out[(size_t)(((row >> 12) * 4 + g) * 4096 + (row & 4095)) << 8] = sqrtf(s);
  }
}

extern "C" void kernel_launch(void* const* d_in, const int* in_sizes, int n_in,
                              void* d_out, int out_size, void* d_ws, size_t ws_size,
                              hipStream_t stream) {
  const float* x    = (const float*)d_in[0];
  const float* W    = (const float*)d_in[1];
  const float* bias = (const float*)d_in[2];
  float* out = (float*)d_out;

  char* ws = (char*)d_ws;
  __hip_bfloat16* Wg = (__hip_bfloat16*)ws;                 // 73728*8*2 = 1179648 B
  float*          T  = (float*)(ws + 1179648);              // 65536 B
  __hip_bfloat16* A  = (__hip_bfloat16*)(ws + 1245184);     // 72*16384*8*2 = 18874368 B

  prep_k<<<400, 512, 0, stream>>>(x, W, A, Wg, T);
  gemm_k<<<1024, 256, 0, stream>>>(A, Wg, W, bias, T, out);
}